// Round 6
// baseline (332.711 us; speedup 1.0000x reference)
//
#include <hip/hip_runtime.h>

#define G_GROUPS 512
#define CNT      8192
#define S_PAIRS  8192
#define BLOCK    1024
#define WAVES    (BLOCK / 64)        // 16
#define PPT      (S_PAIRS / BLOCK)   // 8 pairs per thread
#define HALF     (CNT / 2)           // 4096 records per staging path

typedef __attribute__((address_space(3))) void  lds_void;
typedef const __attribute__((address_space(1))) void g_void;

// Load one CA row (16 B at record byte offset 36r+12; 4B-aligned).
#define LOADCA(dst, src, rec)                                         \
    __builtin_memcpy(&(dst), (src) + (size_t)(rec) * 9 + 3, 16)

// Dual-path staging of one tensor's CA table.
//   waves 0..7 : records [0,4096) via global_load_lds (LDS-DMA queue)
//   waves 8..15: records [4096,8192) via reg-staged VMEM + ds_write
// Role-split pre-barrier waits, then one uniform barrier.
#define DUAL_STAGE(SRC)                                                       \
    if (wid < 8) {                                                            \
        const int rb = wid * 512;                                             \
        _Pragma("unroll")                                                     \
        for (int c = 0; c < 8; ++c) {                                         \
            const int r = rb + c * 64;          /* wave-uniform LDS base */   \
            const float* gp = (SRC) + (size_t)(gbase + r + lane) * 9 + 3;     \
            __builtin_amdgcn_global_load_lds((g_void*)gp,                     \
                                             (lds_void*)&tab4[r], 16, 0, 0);  \
        }                                                                     \
        asm volatile("s_waitcnt vmcnt(0)" ::: "memory");                      \
    } else {                                                                  \
        const int vt = tid - 512;               /* 0..511, lane-contiguous */ \
        const int vb = gbase + HALF + vt;                                     \
        float4 v0, v1, v2, v3, v4, v5, v6, v7;                                \
        LOADCA(v0, SRC, vb + 0 * 512);                                        \
        LOADCA(v1, SRC, vb + 1 * 512);                                        \
        LOADCA(v2, SRC, vb + 2 * 512);                                        \
        LOADCA(v3, SRC, vb + 3 * 512);                                        \
        LOADCA(v4, SRC, vb + 4 * 512);                                        \
        LOADCA(v5, SRC, vb + 5 * 512);                                        \
        LOADCA(v6, SRC, vb + 6 * 512);                                        \
        LOADCA(v7, SRC, vb + 7 * 512);                                        \
        tab4[HALF + vt + 0 * 512] = v0;                                       \
        tab4[HALF + vt + 1 * 512] = v1;                                       \
        tab4[HALF + vt + 2 * 512] = v2;                                       \
        tab4[HALF + vt + 3 * 512] = v3;                                       \
        tab4[HALF + vt + 4 * 512] = v4;                                       \
        tab4[HALF + vt + 5 * 512] = v5;                                       \
        tab4[HALF + vt + 6 * 512] = v6;                                       \
        tab4[HALF + vt + 7 * 512] = v7;                                       \
        asm volatile("s_waitcnt lgkmcnt(0)" ::: "memory");                    \
    }                                                                         \
    __builtin_amdgcn_s_barrier();                                             \
    asm volatile("" ::: "memory");

// Barrier without vmcnt drain (orders LDS reads before table overwrite).
__device__ __forceinline__ void fencebar() {
    asm volatile("s_waitcnt lgkmcnt(0)" ::: "memory");
    __builtin_amdgcn_s_barrier();
    asm volatile("" ::: "memory");
}

__global__ __launch_bounds__(BLOCK, 4) void rgn_loss_kernel(
    const float* __restrict__ inputs,
    const float* __restrict__ target,
    const int*   __restrict__ left,
    const int*   __restrict__ right,
    float*       __restrict__ out)
{
    __shared__ float4 tab4[CNT];          // 128 KiB, one tensor at a time
    __shared__ float  red[WAVES];

    const int tid   = threadIdx.x;
    const int lane  = tid & 63;
    const int wid   = tid >> 6;
    const int g     = blockIdx.x;
    const int gbase = g * CNT;

    // ---- Pair indices: coalesced; retire under the input staging ----
    const size_t pbase = (size_t)g * S_PAIRS;
    int li[PPT], ri[PPT];
    #pragma unroll
    for (int i = 0; i < PPT; ++i) {
        li[i] = left [pbase + tid + i * BLOCK] - gbase;   // group-local by construction
        ri[i] = right[pbase + tid + i * BLOCK] - gbase;
    }

    // ---- Phase 1: inputs table (dual-path) ----
    DUAL_STAGE(inputs)

    // ---- Gather d_in ----
    float din[PPT];
    #pragma unroll
    for (int i = 0; i < PPT; ++i) {
        const float4 L = tab4[li[i]];
        const float4 R = tab4[ri[i]];
        const float dx = L.x - R.x, dy = L.y - R.y, dz = L.z - R.z;
        din[i] = sqrtf(dx * dx + dy * dy + dz * dz);
    }
    fencebar();                            // gather reads done before overwrite

    // ---- Phase 2: target table (dual-path) ----
    DUAL_STAGE(target)

    // ---- Gather d_tg, accumulate ----
    float acc = 0.0f;
    #pragma unroll
    for (int i = 0; i < PPT; ++i) {
        const float4 L = tab4[li[i]];
        const float4 R = tab4[ri[i]];
        const float dx = L.x - R.x, dy = L.y - R.y, dz = L.z - R.z;
        const float d  = din[i] - sqrtf(dx * dx + dy * dy + dz * dz);
        acc += d * d;
    }

    // ---- Block reduction -> one atomic ----
    #pragma unroll
    for (int off = 32; off > 0; off >>= 1)
        acc += __shfl_down(acc, off);
    if (lane == 0) red[wid] = acc;
    __syncthreads();
    if (wid == 0) {
        float v = (lane < WAVES) ? red[lane] : 0.0f;
        #pragma unroll
        for (int off = 8; off > 0; off >>= 1)
            v += __shfl_down(v, off);
        if (lane == 0)
            atomicAdd(out, v * (1.0f / ((float)G_GROUPS * (float)S_PAIRS)));
    }
}

extern "C" void kernel_launch(void* const* d_in, const int* in_sizes, int n_in,
                              void* d_out, int out_size, void* d_ws, size_t ws_size,
                              hipStream_t stream) {
    const float* inputs = (const float*)d_in[0];
    const float* target = (const float*)d_in[1];
    const int*   left   = (const int*)d_in[2];
    const int*   right  = (const int*)d_in[3];
    float*       out    = (float*)d_out;

    hipMemsetAsync(out, 0, sizeof(float), stream);   // graph-capture safe
    rgn_loss_kernel<<<G_GROUPS, BLOCK, 0, stream>>>(inputs, target, left, right, out);
}